// Round 2
// baseline (2701.586 us; speedup 1.0000x reference)
//
#include <hip/hip_runtime.h>
#include <hip/hip_bf16.h>

#define T_  128
#define C_  192
#define H_  6
#define C3_ 576

typedef __bf16 bf16x8 __attribute__((ext_vector_type(8)));
typedef __bf16 bf16x4 __attribute__((ext_vector_type(4)));
typedef float  f32x4  __attribute__((ext_vector_type(4)));

// 8-element MFMA operand fragment: two K=16 slabs, 4 contiguous bf16 each.
__device__ __forceinline__ bf16x8 ld_frag(const __bf16* p) {
    union { bf16x8 v; struct { bf16x4 lo, hi; } s; } u;
    u.s.lo = *reinterpret_cast<const bf16x4*>(p);
    u.s.hi = *reinterpret_cast<const bf16x4*>(p + 16);
    return u.v;
}

__global__ __launch_bounds__(512, 4) void attn_fused(
    const float* __restrict__ x,
    const float* __restrict__ w_qkv,
    const float* __restrict__ b_qkv,
    const float* __restrict__ w_proj,
    const float* __restrict__ b_proj,
    float* __restrict__ y)
{
    // 57344 B total -> 2 blocks/CU. Row strides: k_s 20 words (2-way), vt_s 68
    // words (2-way), w_s 100 words (2-way on b64 reads).
    __shared__ __bf16 k_s[128][40];      // K [s][d], 10240 B
    __shared__ __bf16 vt_s[32][136];     // V^T [d][s], 8704 B
    __shared__ __bf16 w_s[96][200];      // W^T slab [n][k], 38400 B

    const int b    = blockIdx.x;
    const int tid  = threadIdx.x;
    const int wid  = tid >> 6;          // 8 waves
    const int lane = tid & 63;
    const int li   = lane & 15;
    const int g    = lane >> 4;
    const int trow = 16 * wid;          // wave's 16 query rows
    const int tq   = trow + li;         // this lane's query row

    const float scale = 0.17677669529663687f;  // 1/sqrt(32)

    // ---- x B-fragments for rows [trow, trow+16), K=192, kept in regs
    bf16x8 xf[6];
    {
        const float* xr = x + ((size_t)b * T_ + tq) * C_;
        #pragma unroll
        for (int kt = 0; kt < 6; ++kt) {
            f32x4 a0 = *reinterpret_cast<const f32x4*>(xr + kt*32 + 4*g);
            f32x4 a1 = *reinterpret_cast<const f32x4*>(xr + kt*32 + 16 + 4*g);
            bf16x8 f;
            f[0] = (__bf16)a0[0]; f[1] = (__bf16)a0[1]; f[2] = (__bf16)a0[2]; f[3] = (__bf16)a0[3];
            f[4] = (__bf16)a1[0]; f[5] = (__bf16)a1[1]; f[6] = (__bf16)a1[2]; f[7] = (__bf16)a1[3];
            xf[kt] = f;
        }
    }

    bf16x8 of[6];   // per-head attention output fragments (proj A-k-dim tiles)

    #pragma unroll
    for (int h = 0; h < H_; ++h) {
        // ---- stage W_qkv^T slab for head h: rows n_local = sec*32+c (96), cols k
        {
            const int c32 = tid & 31;
            #pragma unroll
            for (int it = 0; it < 12; ++it) {
                const int k = (tid >> 5) + it * 16;
                const float* wr = w_qkv + (size_t)k * C3_ + h * 32 + c32;
                w_s[c32     ][k] = (__bf16)wr[0];
                w_s[32 + c32][k] = (__bf16)wr[192];
                w_s[64 + c32][k] = (__bf16)wr[384];
            }
        }
        __syncthreads();   // w_s ready; also: all waves done with k_s/vt_s reads of h-1

        // ---- QKV GEMM (swapped): C/D lane holds qkv[t=trow+li][n=nt*16+4g+r]
        f32x4 qacc0, qacc1;
        #pragma unroll
        for (int nt = 0; nt < 6; ++nt) {
            const int sec = nt >> 1;
            f32x4 acc = *reinterpret_cast<const f32x4*>(
                &b_qkv[sec * C_ + h * 32 + (nt & 1) * 16 + 4 * g]);
            #pragma unroll
            for (int kt = 0; kt < 6; ++kt) {
                bf16x8 wf = ld_frag(&w_s[nt*16 + li][kt*32 + 4*g]);
                acc = __builtin_amdgcn_mfma_f32_16x16x32_bf16(wf, xf[kt], acc, 0, 0, 0);
            }
            if (nt == 0)      qacc0 = acc;
            else if (nt == 1) qacc1 = acc;
            else if (nt < 4) {      // K -> k_s[s][d], vectorized b64 store
                bf16x4 pk;
                pk[0]=(__bf16)acc[0]; pk[1]=(__bf16)acc[1]; pk[2]=(__bf16)acc[2]; pk[3]=(__bf16)acc[3];
                *reinterpret_cast<bf16x4*>(&k_s[tq][(nt & 1)*16 + 4*g]) = pk;
            } else {                // V -> vt_s[d][s] (transposed, 4 scalar stores)
                #pragma unroll
                for (int r = 0; r < 4; ++r)
                    vt_s[(nt & 1)*16 + 4*g + r][tq] = (__bf16)acc[r];
            }
        }
        // Q fragment directly from accumulator (zero LDS)
        bf16x8 qf;
        #pragma unroll
        for (int j = 0; j < 4; ++j) {
            qf[j]     = (__bf16)qacc0[j];
            qf[4 + j] = (__bf16)qacc1[j];
        }
        __syncthreads();   // k_s / vt_s ready

        // ---- S^T = K·Q^T: lane holds S[tq][key = nt*16+4g+r]; causal skip nt>wid
        f32x4 sacc[8];
        #pragma unroll
        for (int nt = 0; nt < 8; ++nt) {
            if (nt > wid) continue;
            bf16x8 kf = ld_frag(&k_s[nt*16 + li][4*g]);
            f32x4 z = {0.f, 0.f, 0.f, 0.f};
            sacc[nt] = __builtin_amdgcn_mfma_f32_16x16x32_bf16(kf, qf, z, 0, 0, 0);
        }

        // ---- softmax over keys (row = lane's tq): in-lane + 2 shuffles
        float m = -1e30f;
        #pragma unroll
        for (int nt = 0; nt < 8; ++nt) {
            if (nt > wid) continue;
            #pragma unroll
            for (int r = 0; r < 4; ++r) {
                const int key = nt*16 + 4*g + r;
                float v = (key <= tq) ? sacc[nt][r] * scale : -1e30f;
                sacc[nt][r] = v;
                m = fmaxf(m, v);
            }
        }
        m = fmaxf(m, __shfl_xor(m, 16));
        m = fmaxf(m, __shfl_xor(m, 32));
        float l = 0.f;
        #pragma unroll
        for (int nt = 0; nt < 8; ++nt) {
            if (nt > wid) continue;
            #pragma unroll
            for (int r = 0; r < 4; ++r) {
                float p = __expf(sacc[nt][r] - m);
                sacc[nt][r] = p;
                l += p;
            }
        }
        l += __shfl_xor(l, 16);
        l += __shfl_xor(l, 32);

        // ---- PV (swapped): O^T-style, lane holds O[tq][d = m16*16+4g+r]
        f32x4 o0 = {0.f,0.f,0.f,0.f}, o1 = {0.f,0.f,0.f,0.f};
        #pragma unroll
        for (int kk = 0; kk < 4; ++kk) {
            if (2*kk > wid) continue;
            bf16x8 pf;
            #pragma unroll
            for (int j = 0; j < 4; ++j) {
                pf[j]     = (__bf16)sacc[2*kk][j];
                pf[4 + j] = (2*kk + 1 <= wid) ? (__bf16)sacc[2*kk + 1][j] : (__bf16)0.f;
            }
            bf16x8 vf0 = ld_frag(&vt_s[li     ][kk*32 + 4*g]);
            bf16x8 vf1 = ld_frag(&vt_s[16 + li][kk*32 + 4*g]);
            o0 = __builtin_amdgcn_mfma_f32_16x16x32_bf16(vf0, pf, o0, 0, 0, 0);
            o1 = __builtin_amdgcn_mfma_f32_16x16x32_bf16(vf1, pf, o1, 0, 0, 0);
        }
        const float rl = 1.f / l;
        #pragma unroll
        for (int j = 0; j < 4; ++j) {
            of[h][j]     = (__bf16)(o0[j] * rl);
            of[h][4 + j] = (__bf16)(o1[j] * rl);
        }
    }

    // ---- projection: y = O @ W_proj + b, swapped; O fragments already in regs
    float* yr = y + (size_t)b * T_ * C_;
    #pragma unroll
    for (int chunk = 0; chunk < 2; ++chunk) {
        __syncthreads();   // all waves done reading w_s (prev GEMM)
        {
            const int c32 = tid & 31;
            #pragma unroll
            for (int it = 0; it < 12; ++it) {
                const int k = (tid >> 5) + it * 16;
                const float* wr = w_proj + (size_t)k * C_ + chunk * 96 + c32;
                w_s[c32     ][k] = (__bf16)wr[0];
                w_s[32 + c32][k] = (__bf16)wr[32];
                w_s[64 + c32][k] = (__bf16)wr[64];
            }
        }
        __syncthreads();
        #pragma unroll
        for (int nt = 0; nt < 6; ++nt) {
            f32x4 acc = *reinterpret_cast<const f32x4*>(
                &b_proj[chunk * 96 + nt*16 + 4*g]);
            #pragma unroll
            for (int kt = 0; kt < 6; ++kt) {
                bf16x8 wf = ld_frag(&w_s[nt*16 + li][kt*32 + 4*g]);
                acc = __builtin_amdgcn_mfma_f32_16x16x32_bf16(wf, of[kt], acc, 0, 0, 0);
            }
            // lane: row t=tq, cols chunk*96+nt*16+4g+{0..3} -> coalesced f32x4 store
            *reinterpret_cast<f32x4*>(&yr[(size_t)tq * C_ + chunk*96 + nt*16 + 4*g]) = acc;
        }
    }
}

extern "C" void kernel_launch(void* const* d_in, const int* in_sizes, int n_in,
                              void* d_out, int out_size, void* d_ws, size_t ws_size,
                              hipStream_t stream) {
    const float* x      = (const float*)d_in[0];
    const float* w_qkv  = (const float*)d_in[1];
    const float* b_qkv  = (const float*)d_in[2];
    const float* w_proj = (const float*)d_in[3];
    const float* b_proj = (const float*)d_in[4];
    float* yv = (float*)d_out;
    const int B = in_sizes[0] / (T_ * C_);
    attn_fused<<<B, 512, 0, stream>>>(x, w_qkv, b_qkv, w_proj, b_proj, yv);
}

// Round 3
// 494.678 us; speedup vs baseline: 5.4613x; 5.4613x over previous
//
#include <hip/hip_runtime.h>
#include <hip/hip_bf16.h>

#define T_  128
#define C_  192
#define H_  6
#define C3_ 576

typedef __bf16 bf16x8 __attribute__((ext_vector_type(8)));
typedef __bf16 bf16x4 __attribute__((ext_vector_type(4)));
typedef float  f32x4  __attribute__((ext_vector_type(4)));

// XOR-swizzle for w_s columns: permutes 4-element (8B) blocks within a
// 16-element span, keyed by row bits 3-4. Store and load apply identically.
#define WSWZ(n_, k_) ((k_) ^ ((((n_) >> 3) & 3) << 2))

// 8-element MFMA operand fragment: two K=16 slabs, 4 contiguous bf16 each.
// (Safe with WSWZ'd base: +16 only flips bit 4, untouched by the swizzle.)
__device__ __forceinline__ bf16x8 ld_frag(const __bf16* p) {
    union { bf16x8 v; struct { bf16x4 lo, hi; } s; } u;
    u.s.lo = *reinterpret_cast<const bf16x4*>(p);
    u.s.hi = *reinterpret_cast<const bf16x4*>(p + 16);
    return u.v;
}

__global__ __launch_bounds__(512) void attn_fused(
    const float* __restrict__ x,
    const float* __restrict__ w_qkv,
    const float* __restrict__ b_qkv,
    const float* __restrict__ w_proj,
    const float* __restrict__ b_proj,
    float* __restrict__ y)
{
    // 57344 B total -> 2 blocks/CU if VGPR <= 128.
    __shared__ __bf16 k_s[128][40];      // K [s][d], 10240 B
    __shared__ __bf16 vt_s[32][136];     // V^T [d][s], 8704 B
    __shared__ __bf16 w_s[96][200];      // W^T slab [n][k] (k swizzled), 38400 B

    const int b    = blockIdx.x;
    const int tid  = threadIdx.x;
    const int wid  = tid >> 6;          // 8 waves
    const int lane = tid & 63;
    const int li   = lane & 15;
    const int g    = lane >> 4;
    const int trow = 16 * wid;          // wave's 16 query rows
    const int tq   = trow + li;         // this lane's query row

    const float scale = 0.17677669529663687f;  // 1/sqrt(32)

    // ---- x B-fragments for rows [trow, trow+16), K=192, kept in regs
    bf16x8 xf[6];
    {
        const float* xr = x + ((size_t)b * T_ + tq) * C_;
        #pragma unroll
        for (int kt = 0; kt < 6; ++kt) {
            f32x4 a0 = *reinterpret_cast<const f32x4*>(xr + kt*32 + 4*g);
            f32x4 a1 = *reinterpret_cast<const f32x4*>(xr + kt*32 + 16 + 4*g);
            bf16x8 f;
            f[0] = (__bf16)a0[0]; f[1] = (__bf16)a0[1]; f[2] = (__bf16)a0[2]; f[3] = (__bf16)a0[3];
            f[4] = (__bf16)a1[0]; f[5] = (__bf16)a1[1]; f[6] = (__bf16)a1[2]; f[7] = (__bf16)a1[3];
            xf[kt] = f;
        }
    }

    bf16x8 of[6];   // per-head attention output fragments (proj A-k-dim tiles)

    #pragma unroll
    for (int h = 0; h < H_; ++h) {
        // ---- stage W_qkv^T slab for head h: rows n_local = sec*32+c (96), cols k
        {
            const int c32 = tid & 31;
            #pragma unroll
            for (int it = 0; it < 12; ++it) {
                const int k = (tid >> 5) + it * 16;
                const float* wr = w_qkv + (size_t)k * C3_ + h * 32 + c32;
                const int ks = WSWZ(c32, k);   // same swizzle key for all 3 sections
                w_s[c32     ][ks] = (__bf16)wr[0];
                w_s[32 + c32][ks] = (__bf16)wr[192];
                w_s[64 + c32][ks] = (__bf16)wr[384];
            }
        }
        __syncthreads();   // w_s ready; also: all waves done with k_s/vt_s reads of h-1

        // ---- QKV GEMM (swapped): C/D lane holds qkv[t=trow+li][n=nt*16+4g+r]
        f32x4 qacc0, qacc1;
        #pragma unroll
        for (int nt = 0; nt < 6; ++nt) {
            const int sec = nt >> 1;
            const int n   = nt * 16 + li;
            f32x4 acc = *reinterpret_cast<const f32x4*>(
                &b_qkv[sec * C_ + h * 32 + (nt & 1) * 16 + 4 * g]);
            #pragma unroll
            for (int kt = 0; kt < 6; ++kt) {
                bf16x8 wf = ld_frag(&w_s[n][WSWZ(n, kt*32 + 4*g)]);
                acc = __builtin_amdgcn_mfma_f32_16x16x32_bf16(wf, xf[kt], acc, 0, 0, 0);
            }
            if (nt == 0)      qacc0 = acc;
            else if (nt == 1) qacc1 = acc;
            else if (nt < 4) {      // K -> k_s[s][d], vectorized b64 store
                bf16x4 pk;
                pk[0]=(__bf16)acc[0]; pk[1]=(__bf16)acc[1]; pk[2]=(__bf16)acc[2]; pk[3]=(__bf16)acc[3];
                *reinterpret_cast<bf16x4*>(&k_s[tq][(nt & 1)*16 + 4*g]) = pk;
            } else {                // V -> vt_s[d][s] (transposed, 4 scalar stores)
                #pragma unroll
                for (int r = 0; r < 4; ++r)
                    vt_s[(nt & 1)*16 + 4*g + r][tq] = (__bf16)acc[r];
            }
        }
        // Q fragment directly from accumulator (zero LDS)
        bf16x8 qf;
        #pragma unroll
        for (int j = 0; j < 4; ++j) {
            qf[j]     = (__bf16)qacc0[j];
            qf[4 + j] = (__bf16)qacc1[j];
        }
        __syncthreads();   // k_s / vt_s ready

        // ---- S^T = K·Q^T: lane holds S[tq][key = nt*16+4g+r]; causal skip nt>wid
        f32x4 sacc[8];
        #pragma unroll
        for (int nt = 0; nt < 8; ++nt) {
            if (nt > wid) continue;
            bf16x8 kf = ld_frag(&k_s[nt*16 + li][4*g]);
            f32x4 z = {0.f, 0.f, 0.f, 0.f};
            sacc[nt] = __builtin_amdgcn_mfma_f32_16x16x32_bf16(kf, qf, z, 0, 0, 0);
        }

        // ---- softmax over keys (row = lane's tq): in-lane + 2 shuffles
        float m = -1e30f;
        #pragma unroll
        for (int nt = 0; nt < 8; ++nt) {
            if (nt > wid) continue;
            #pragma unroll
            for (int r = 0; r < 4; ++r) {
                const int key = nt*16 + 4*g + r;
                float v = (key <= tq) ? sacc[nt][r] * scale : -1e30f;
                sacc[nt][r] = v;
                m = fmaxf(m, v);
            }
        }
        m = fmaxf(m, __shfl_xor(m, 16));
        m = fmaxf(m, __shfl_xor(m, 32));
        float l = 0.f;
        #pragma unroll
        for (int nt = 0; nt < 8; ++nt) {
            if (nt > wid) continue;
            #pragma unroll
            for (int r = 0; r < 4; ++r) {
                float p = __expf(sacc[nt][r] - m);
                sacc[nt][r] = p;
                l += p;
            }
        }
        l += __shfl_xor(l, 16);
        l += __shfl_xor(l, 32);

        // ---- PV (swapped): lane holds O[tq][d = m16*16+4g+r]
        f32x4 o0 = {0.f,0.f,0.f,0.f}, o1 = {0.f,0.f,0.f,0.f};
        #pragma unroll
        for (int kk = 0; kk < 4; ++kk) {
            if (2*kk > wid) continue;
            bf16x8 pf;
            #pragma unroll
            for (int j = 0; j < 4; ++j) {
                pf[j]     = (__bf16)sacc[2*kk][j];
                pf[4 + j] = (2*kk + 1 <= wid) ? (__bf16)sacc[2*kk + 1][j] : (__bf16)0.f;
            }
            bf16x8 vf0 = ld_frag(&vt_s[li     ][kk*32 + 4*g]);
            bf16x8 vf1 = ld_frag(&vt_s[16 + li][kk*32 + 4*g]);
            o0 = __builtin_amdgcn_mfma_f32_16x16x32_bf16(vf0, pf, o0, 0, 0, 0);
            o1 = __builtin_amdgcn_mfma_f32_16x16x32_bf16(vf1, pf, o1, 0, 0, 0);
        }
        const float rl = 1.f / l;
        #pragma unroll
        for (int j = 0; j < 4; ++j) {
            of[h][j]     = (__bf16)(o0[j] * rl);
            of[h][4 + j] = (__bf16)(o1[j] * rl);
        }
    }

    // ---- projection: y = O @ W_proj + b, swapped; O fragments already in regs
    float* yr = y + (size_t)b * T_ * C_;
    #pragma unroll
    for (int chunk = 0; chunk < 2; ++chunk) {
        __syncthreads();   // all waves done reading w_s (prev GEMM)
        {
            const int c32 = tid & 31;
            #pragma unroll
            for (int it = 0; it < 12; ++it) {
                const int k = (tid >> 5) + it * 16;
                const float* wr = w_proj + (size_t)k * C_ + chunk * 96 + c32;
                const int ks = WSWZ(c32, k);
                w_s[c32     ][ks] = (__bf16)wr[0];
                w_s[32 + c32][ks] = (__bf16)wr[32];
                w_s[64 + c32][ks] = (__bf16)wr[64];
            }
        }
        __syncthreads();
        #pragma unroll
        for (int nt = 0; nt < 6; ++nt) {
            const int n = nt * 16 + li;
            f32x4 acc = *reinterpret_cast<const f32x4*>(
                &b_proj[chunk * 96 + nt*16 + 4*g]);
            #pragma unroll
            for (int kt = 0; kt < 6; ++kt) {
                bf16x8 wf = ld_frag(&w_s[n][WSWZ(n, kt*32 + 4*g)]);
                acc = __builtin_amdgcn_mfma_f32_16x16x32_bf16(wf, of[kt], acc, 0, 0, 0);
            }
            // lane: row t=tq, cols chunk*96+nt*16+4g+{0..3} -> coalesced f32x4 store
            *reinterpret_cast<f32x4*>(&yr[(size_t)tq * C_ + chunk*96 + nt*16 + 4*g]) = acc;
        }
    }
}

extern "C" void kernel_launch(void* const* d_in, const int* in_sizes, int n_in,
                              void* d_out, int out_size, void* d_ws, size_t ws_size,
                              hipStream_t stream) {
    const float* x      = (const float*)d_in[0];
    const float* w_qkv  = (const float*)d_in[1];
    const float* b_qkv  = (const float*)d_in[2];
    const float* w_proj = (const float*)d_in[3];
    const float* b_proj = (const float*)d_in[4];
    float* yv = (float*)d_out;
    const int B = in_sizes[0] / (T_ * C_);
    attn_fused<<<B, 512, 0, stream>>>(x, w_qkv, b_qkv, w_proj, b_proj, yv);
}